// Round 4
// baseline (598.684 us; speedup 1.0000x reference)
//
#include <hip/hip_runtime.h>
#include <cstdint>
#include <type_traits>

typedef __attribute__((ext_vector_type(8))) short short8;
typedef __attribute__((ext_vector_type(4))) float floatx4;

#define NB 2
#define NS 2048
#define ND 2048
#define NH 16
#define NHD 128

__device__ __forceinline__ float b2f(short s) {
  unsigned u = ((unsigned)(unsigned short)s) << 16;
  return __builtin_bit_cast(float, u);
}
__device__ __forceinline__ short f2b(float f) {
  unsigned u = __builtin_bit_cast(unsigned, f);
  unsigned r = (u + 0x7fffu + ((u >> 16) & 1u)) >> 16;
  return (short)(unsigned short)r;
}

// ---------------- fused cast: x|wq|wk|wv|wo -> contiguous bf16 ws [xb|wqkvb|wob] -------
__global__ void cast_all(const float* __restrict__ x, const float* __restrict__ wq,
                         const float* __restrict__ wk, const float* __restrict__ wv,
                         const float* __restrict__ wo, short* __restrict__ dst) {
  const int i = blockIdx.x * blockDim.x + threadIdx.x;  // short4 units, block-uniform ranges
  const float* src;
  int off;
  if (i < 2097152) { src = x;  off = i; }
  else if (i < 3145728) { src = wq; off = i - 2097152; }
  else if (i < 4194304) { src = wk; off = i - 3145728; }
  else if (i < 5242880) { src = wv; off = i - 4194304; }
  else { src = wo; off = i - 5242880; }
  float4 v = ((const float4*)src)[off];
  short4 o;
  o.x = f2b(v.x); o.y = f2b(v.y); o.z = f2b(v.z); o.w = f2b(v.w);
  ((short4*)dst)[i] = o;
}

// ---------------- async global->LDS, 16B/lane ----------------
__device__ __forceinline__ void gld_lds16(const void* g, void* l) {
  __builtin_amdgcn_global_load_lds((const __attribute__((address_space(1))) void*)g,
                                   (__attribute__((address_space(3))) void*)l,
                                   16, 0, 0);
}

// ---------------- fused QKV GEMM, BK=64, XOR-swizzled LDS (proven 128^2, 838 TF) --------
// C = x (4096x2048) * Wqkv^T (6144x2048). col-block: 0-15 Q head-major, 16-31 K head-major,
// 32-47 V token-major. LDS[r][c] holds global chunk c^(r&7) (16B chunks, 8/row).
// R2 lesson: 256^2 4-phase/2-buffer dbuf regressed (vmcnt(0) drain at 1.5-2.5-phase
// distance < HBM latency; XCD swizzle raised FETCH 106->176MB). A retry needs the true
// m201 half-tile ring + counted vmcnt(6).
__global__ __launch_bounds__(256) void qkv_gemm(const short* __restrict__ A,
                                                const short* __restrict__ Bt,
                                                short* __restrict__ Qh,
                                                short* __restrict__ Kh,
                                                short* __restrict__ vlin) {
  constexpr int K = 2048;
  __shared__ short As[128 * 64];
  __shared__ short Bs[128 * 64];
  const int m0 = blockIdx.y * 128, n0 = blockIdx.x * 128;
  const int which = n0 >> 11;
  const int nl0 = n0 & 2047;
  const int t = threadIdx.x;
  const int wave = t >> 6, lane = t & 63, l15 = lane & 15, quad = lane >> 4;
  const int wm = (wave >> 1) * 64, wn = (wave & 1) * 64;

  floatx4 acc[4][4] = {};

  const int srow = t >> 3;                  // 0..31
  const int scol = (t & 7) ^ (srow & 7);    // swizzled global chunk for this lane
  const short* Ag = A + (long)(m0 + srow) * K + scol * 8;
  const short* Bg = Bt + (long)(n0 + srow) * K + scol * 8;
  char* AsB = (char*)As;
  char* BsB = (char*)Bs;
  const int ldsOff = wave * 1024;  // 8 rows x 128 B per wave

  for (int kt = 0; kt < K; kt += 64) {
#pragma unroll
    for (int i = 0; i < 4; ++i) {
      gld_lds16(Ag + kt + (long)(32 * i) * K, AsB + ldsOff + i * 4096);
      gld_lds16(Bg + kt + (long)(32 * i) * K, BsB + ldsOff + i * 4096);
    }
    __syncthreads();

#pragma unroll
    for (int half = 0; half < 2; ++half) {
      short8 a[4], b[4];
#pragma unroll
      for (int mi = 0; mi < 4; ++mi) {
        const int rr = wm + mi * 16 + l15;
        a[mi] = *(const short8*)&As[rr * 64 + (((half << 2) | quad) ^ (rr & 7)) * 8];
      }
#pragma unroll
      for (int ni = 0; ni < 4; ++ni) {
        const int rr = wn + ni * 16 + l15;
        b[ni] = *(const short8*)&Bs[rr * 64 + (((half << 2) | quad) ^ (rr & 7)) * 8];
      }
#pragma unroll
      for (int mi = 0; mi < 4; ++mi)
#pragma unroll
        for (int ni = 0; ni < 4; ++ni)
          acc[mi][ni] = __builtin_amdgcn_mfma_f32_16x16x32_bf16(a[mi], b[ni], acc[mi][ni], 0, 0, 0);
    }
    __syncthreads();
  }

  short* headDst = (which == 0) ? Qh : Kh;
#pragma unroll
  for (int mi = 0; mi < 4; ++mi) {
#pragma unroll
    for (int ni = 0; ni < 4; ++ni) {
#pragma unroll
      for (int r = 0; r < 4; ++r) {
        const int row = m0 + wm + mi * 16 + quad * 4 + r;
        const int col = nl0 + wn + ni * 16 + l15;
        const short v = f2b(acc[mi][ni][r]);
        if (which == 2) {
          vlin[(long)row * 2048 + col] = v;
        } else {
          const int bb = row >> 11, s = row & 2047, h = col >> 7, hd = col & 127;
          headDst[(((long)(bb * 16 + h) * 2048) + s) * 128 + hd] = v;
        }
      }
    }
  }
}

// ---------------- output GEMM: fp32 out, token-major; BK=64 swizzled ----------------
__global__ __launch_bounds__(256) void gemm_out(const short* __restrict__ A,
                                                const short* __restrict__ Bt,
                                                float* __restrict__ Cout) {
  constexpr int K = 2048, N = 2048;
  __shared__ short As[128 * 64];
  __shared__ short Bs[128 * 64];
  const int m0 = blockIdx.y * 128, n0 = blockIdx.x * 128;
  const int t = threadIdx.x;
  const int wave = t >> 6, lane = t & 63, l15 = lane & 15, quad = lane >> 4;
  const int wm = (wave >> 1) * 64, wn = (wave & 1) * 64;

  floatx4 acc[4][4] = {};

  const int srow = t >> 3;
  const int scol = (t & 7) ^ (srow & 7);
  const short* Ag = A + (long)(m0 + srow) * K + scol * 8;
  const short* Bg = Bt + (long)(n0 + srow) * K + scol * 8;
  char* AsB = (char*)As;
  char* BsB = (char*)Bs;
  const int ldsOff = wave * 1024;

  for (int kt = 0; kt < K; kt += 64) {
#pragma unroll
    for (int i = 0; i < 4; ++i) {
      gld_lds16(Ag + kt + (long)(32 * i) * K, AsB + ldsOff + i * 4096);
      gld_lds16(Bg + kt + (long)(32 * i) * K, BsB + ldsOff + i * 4096);
    }
    __syncthreads();

#pragma unroll
    for (int half = 0; half < 2; ++half) {
      short8 a[4], b[4];
#pragma unroll
      for (int mi = 0; mi < 4; ++mi) {
        const int rr = wm + mi * 16 + l15;
        a[mi] = *(const short8*)&As[rr * 64 + (((half << 2) | quad) ^ (rr & 7)) * 8];
      }
#pragma unroll
      for (int ni = 0; ni < 4; ++ni) {
        const int rr = wn + ni * 16 + l15;
        b[ni] = *(const short8*)&Bs[rr * 64 + (((half << 2) | quad) ^ (rr & 7)) * 8];
      }
#pragma unroll
      for (int mi = 0; mi < 4; ++mi)
#pragma unroll
        for (int ni = 0; ni < 4; ++ni)
          acc[mi][ni] = __builtin_amdgcn_mfma_f32_16x16x32_bf16(a[mi], b[ni], acc[mi][ni], 0, 0, 0);
    }
    __syncthreads();
  }

#pragma unroll
  for (int mi = 0; mi < 4; ++mi)
#pragma unroll
    for (int ni = 0; ni < 4; ++ni)
#pragma unroll
      for (int r = 0; r < 4; ++r) {
        const int row = m0 + wm + mi * 16 + quad * 4 + r;
        const int col = n0 + wn + ni * 16 + l15;
        Cout[(long)row * N + col] = acc[mi][ni][r];
      }
}

// ------------- merged RoPE (blocks 0..4095) + V transpose (blocks 4096..6143) -------------
__global__ __launch_bounds__(256) void rope_vtrans(short* __restrict__ Qh,
                                                   short* __restrict__ Kh,
                                                   const float* __restrict__ pos,
                                                   const short* __restrict__ v_lin,
                                                   short* __restrict__ Vt) {
  __shared__ short tile[64 * 72];
  const int bx = blockIdx.x;
  if (bx < 4096) {
    // ---- RoPE in-place on head-major Q,K: 4096 blocks x 256 = token(4096) x h(16) x kk(16)
    const int tid = bx * 256 + threadIdx.x;
    const int kk = tid & 15;
    const int h = (tid >> 4) & 15;
    const int token = tid >> 8;
    const int bb = token >> 11, s = token & 2047;
    const float4 p4 = ((const float4*)pos)[token];
    const float pv[4] = {p4.x, p4.y, p4.z, p4.w};
    const float theta = exp2f(-(float)kk * 0.8304820237218406f);
    const long base = (((long)(bb * 16 + h)) * 2048 + s) * 128 + kk * 8;
    short8 q8 = *(short8*)(Qh + base);
    short8 k8 = *(short8*)(Kh + base);
    short8 qo, ko;
#pragma unroll
    for (int jj = 0; jj < 4; ++jj) {
      const float fr = pv[jj] * theta;
      float sn, c;
      __sincosf(fr, &sn, &c);
      {
        const float tr = b2f(q8[2 * jj]), ti = b2f(q8[2 * jj + 1]);
        qo[2 * jj] = f2b(tr * c - ti * sn);
        qo[2 * jj + 1] = f2b(tr * sn + ti * c);
      }
      {
        const float tr = b2f(k8[2 * jj]), ti = b2f(k8[2 * jj + 1]);
        ko[2 * jj] = f2b(tr * c - ti * sn);
        ko[2 * jj + 1] = f2b(tr * sn + ti * c);
      }
    }
    *(short8*)(Qh + base) = qo;
    *(short8*)(Kh + base) = ko;
  } else {
    // ---- V transpose: vlin [token][h*128+hd] -> Vt [b][h][hd][s] ----
    const int b2 = bx - 4096;  // 0..2047
    const int s0 = (b2 & 31) * 64;
    const int hd0 = ((b2 >> 5) & 1) * 64;
    const int bh = b2 >> 6;
    const int bb = bh >> 4, h = bh & 15;
    const int t = threadIdx.x;
#pragma unroll
    for (int i = 0; i < 2; ++i) {
      const int ch = t + i * 256;
      const int r = ch >> 3, c = ch & 7;
      *(short8*)&tile[r * 72 + c * 8] =
          *(const short8*)(v_lin + (long)(bb * 2048 + s0 + r) * 2048 + h * 128 + hd0 + c * 8);
    }
    __syncthreads();
#pragma unroll
    for (int i = 0; i < 2; ++i) {
      const int ch = t + i * 256;
      const int r2 = ch >> 3, c2 = ch & 7;
      short8 o;
#pragma unroll
      for (int u = 0; u < 8; ++u) o[u] = tile[(c2 * 8 + u) * 72 + r2];
      *(short8*)(Vt + ((long)(bh * 128 + hd0 + r2)) * 2048 + s0 + c2 * 8) = o;
    }
  }
}

// ---------------- flash attention v3: BARRIER-FREE, direct-from-L2 K/V ----------------
// R4 theory: flash is chain-latency-bound (R3: dur == 32 steps x 5.2us == longest block's
// chain; TLP tripling didn't change step time; all pipes <19% busy). The K/V LDS tiles
// were read with wave-uniform addresses (all 4 waves identical data), so staging bought
// nothing except two barriers per step. Drop ALL staging: read K/V fragments directly
// from global (L1/L2-served; K-slice 16KB fits L1), keep only wave-private Ps ->
// ZERO __syncthreads in the kernel. 16 independent wave-chains per CU (4 blocks x 4 waves,
// LDS 9.2KB, launch_bounds(256,4)).
// Block id -> (qt,bh) mirror map: ids k,k+256 have complementary qt so any round-robin
// 4-block-per-CU assignment gets balanced work (sum=66 steps).
__global__ __launch_bounds__(256, 4) void flash(const short* __restrict__ Qh,
                                                const short* __restrict__ Kh,
                                                const short* __restrict__ Vt,
                                                short* __restrict__ ao) {
  __shared__ short Ps[4 * 16 * 72];  // 9216 B, wave-private regions
  const int id = blockIdx.x;  // 0..1023
  const int hi = id >> 8, lo = id & 255;
  const int q0 = lo & 31, bl = lo >> 5;
  const int qt = (hi & 1) ? 31 - q0 : q0;   // mirror on odd hi-pages
  const int bh = bl + (hi << 3);            // 0..31, bijective with (qt,bh)
  const int t = threadIdx.x, wave = t >> 6, lane = t & 63, l15 = lane & 15, quad = lane >> 4;
  const int sqb = qt * 64;
  const int lastkt = qt;

  const short* Qbase = Qh + (long)bh * 2048 * 128;
  short8 aq[4];
#pragma unroll
  for (int ks = 0; ks < 4; ++ks)
    aq[ks] = *(const short8*)(Qbase + (long)(sqb + wave * 16 + l15) * 128 + ks * 32 + quad * 8);

  const short* KgBase = Kh + (long)bh * 2048 * 128;
  const short* VgBase = Vt + (long)bh * 128 * 2048;

  float l_part[4] = {};
  floatx4 acc_o[8] = {};
  const float CEXP = 0.12751745f;  // (1/sqrt(128)) * log2(e)

  for (int kt = 0; kt <= lastkt; ++kt) {
    const int k0 = kt * 64;
    const bool dg = (kt == lastkt);

    // ---- QK^T: K fragments straight from global (row = k0+ni*16+l15, 16B per lane) ----
    floatx4 accs[4] = {};
    __builtin_amdgcn_s_setprio(1);
#pragma unroll
    for (int ks = 0; ks < 4; ++ks) {
#pragma unroll
      for (int ni = 0; ni < 4; ++ni) {
        const short8 bk =
            *(const short8*)(KgBase + (long)(k0 + ni * 16 + l15) * 128 + ks * 32 + quad * 8);
        accs[ni] = __builtin_amdgcn_mfma_f32_16x16x32_bf16(aq[ks], bk, accs[ni], 0, 0, 0);
      }
    }
    __builtin_amdgcn_s_setprio(0);

    // ---- softmax numerator -> Ps (wave-private; same-wave write->read, no barrier) ----
#pragma unroll
    for (int r = 0; r < 4; ++r) {
      const int qrow = sqb + wave * 16 + quad * 4 + r;
#pragma unroll
      for (int ni = 0; ni < 4; ++ni) {
        float e = exp2f(accs[ni][r] * CEXP);
        if (dg && (k0 + ni * 16 + l15) > qrow) e = 0.f;
        Ps[wave * 1152 + (quad * 4 + r) * 72 + ni * 16 + l15] = f2b(e);
        l_part[r] += e;
      }
    }

    // ---- PV: V^T fragments straight from global (row = hd, col = s, 16B per lane) ----
    __builtin_amdgcn_s_setprio(1);
#pragma unroll
    for (int ks2 = 0; ks2 < 2; ++ks2) {
      const short8 ap = *(const short8*)&Ps[wave * 1152 + l15 * 72 + ks2 * 32 + quad * 8];
#pragma unroll
      for (int nh = 0; nh < 8; ++nh) {
        const short8 bv =
            *(const short8*)(VgBase + (long)(nh * 16 + l15) * 2048 + k0 + ks2 * 32 + quad * 8);
        acc_o[nh] = __builtin_amdgcn_mfma_f32_16x16x32_bf16(ap, bv, acc_o[nh], 0, 0, 0);
      }
    }
    __builtin_amdgcn_s_setprio(0);
  }

  const int bb = bh >> 4, h = bh & 15;
#pragma unroll
  for (int r = 0; r < 4; ++r) {
    float rs = l_part[r];
#pragma unroll
    for (int mm = 8; mm >= 1; mm >>= 1) rs += __shfl_xor(rs, mm, 16);
    const float inv = 1.0f / rs;
    const int s = sqb + wave * 16 + quad * 4 + r;
    const long rowbase = ((long)(bb * 2048 + s)) * 2048 + h * 128;
#pragma unroll
    for (int nh = 0; nh < 8; ++nh) ao[rowbase + nh * 16 + l15] = f2b(acc_o[nh][r] * inv);
  }
}

extern "C" void kernel_launch(void* const* d_in, const int* in_sizes, int n_in,
                              void* d_out, int out_size, void* d_ws, size_t ws_size,
                              hipStream_t stream) {
  const float* x = (const float*)d_in[0];
  const float* pos = (const float*)d_in[1];
  const float* wq = (const float*)d_in[3];
  const float* wk = (const float*)d_in[4];
  const float* wv = (const float*)d_in[5];
  const float* wo = (const float*)d_in[6];
  float* out = (float*)d_out;

  char* ws = (char*)d_ws;
  const size_t MB = 1024 * 1024;
  short* xb    = (short*)(ws + 0);        // 16 MB
  short* wqkvb = (short*)(ws + 16 * MB);  // 24 MB
  short* wob   = (short*)(ws + 40 * MB);  // 8 MB
  short* Qh    = (short*)(ws + 48 * MB);  // 16 MB
  short* Kh    = (short*)(ws + 64 * MB);  // 16 MB
  short* Vt    = (short*)(ws + 80 * MB);  // 16 MB
  short* vlin  = (short*)(ws + 96 * MB);  // 16 MB
  short* ao    = (short*)(ws + 96 * MB);  // alias vlin (vtrans consumes vlin before flash)
  // total 112 MB

  cast_all<<<24576, 256, 0, stream>>>(x, wq, wk, wv, wo, xb);

  qkv_gemm<<<dim3(48, 32), 256, 0, stream>>>(xb, wqkvb, Qh, Kh, vlin);

  rope_vtrans<<<6144, 256, 0, stream>>>(Qh, Kh, pos, vlin, Vt);

  flash<<<1024, 256, 0, stream>>>(Qh, Kh, Vt, ao);

  gemm_out<<<dim3(16, 32), 256, 0, stream>>>(ao, wob, out);
}

// Round 5
// 582.799 us; speedup vs baseline: 1.0273x; 1.0273x over previous
//
#include <hip/hip_runtime.h>
#include <cstdint>
#include <type_traits>

typedef __attribute__((ext_vector_type(8))) short short8;
typedef __attribute__((ext_vector_type(4))) float floatx4;

#define NB 2
#define NS 2048
#define ND 2048
#define NH 16
#define NHD 128

__device__ __forceinline__ float b2f(short s) {
  unsigned u = ((unsigned)(unsigned short)s) << 16;
  return __builtin_bit_cast(float, u);
}
__device__ __forceinline__ short f2b(float f) {
  unsigned u = __builtin_bit_cast(unsigned, f);
  unsigned r = (u + 0x7fffu + ((u >> 16) & 1u)) >> 16;
  return (short)(unsigned short)r;
}

// ---------------- fused cast: x|wq|wk|wv|wo -> contiguous bf16 ws [xb|wqkvb|wob] -------
__global__ void cast_all(const float* __restrict__ x, const float* __restrict__ wq,
                         const float* __restrict__ wk, const float* __restrict__ wv,
                         const float* __restrict__ wo, short* __restrict__ dst) {
  const int i = blockIdx.x * blockDim.x + threadIdx.x;  // short4 units, block-uniform ranges
  const float* src;
  int off;
  if (i < 2097152) { src = x;  off = i; }
  else if (i < 3145728) { src = wq; off = i - 2097152; }
  else if (i < 4194304) { src = wk; off = i - 3145728; }
  else if (i < 5242880) { src = wv; off = i - 4194304; }
  else { src = wo; off = i - 5242880; }
  float4 v = ((const float4*)src)[off];
  short4 o;
  o.x = f2b(v.x); o.y = f2b(v.y); o.z = f2b(v.z); o.w = f2b(v.w);
  ((short4*)dst)[i] = o;
}

// ---------------- async global->LDS, 16B/lane ----------------
__device__ __forceinline__ void gld_lds16(const void* g, void* l) {
  __builtin_amdgcn_global_load_lds((const __attribute__((address_space(1))) void*)g,
                                   (__attribute__((address_space(3))) void*)l,
                                   16, 0, 0);
}

// ---------------- fused QKV GEMM, BK=64, XOR-swizzled LDS (proven 128^2, 838 TF) --------
// C = x (4096x2048) * Wqkv^T (6144x2048). col-block: 0-15 Q head-major, 16-31 K head-major,
// 32-47 V token-major. LDS[r][c] holds global chunk c^(r&7) (16B chunks, 8/row).
// R2 lesson: 256^2 4-phase/2-buffer dbuf regressed (vmcnt(0) drain at 1.5-2.5-phase
// distance < HBM latency; XCD swizzle raised FETCH 106->176MB). A retry needs the true
// m201 half-tile ring + counted vmcnt(6).
__global__ __launch_bounds__(256) void qkv_gemm(const short* __restrict__ A,
                                                const short* __restrict__ Bt,
                                                short* __restrict__ Qh,
                                                short* __restrict__ Kh,
                                                short* __restrict__ vlin) {
  constexpr int K = 2048;
  __shared__ short As[128 * 64];
  __shared__ short Bs[128 * 64];
  const int m0 = blockIdx.y * 128, n0 = blockIdx.x * 128;
  const int which = n0 >> 11;
  const int nl0 = n0 & 2047;
  const int t = threadIdx.x;
  const int wave = t >> 6, lane = t & 63, l15 = lane & 15, quad = lane >> 4;
  const int wm = (wave >> 1) * 64, wn = (wave & 1) * 64;

  floatx4 acc[4][4] = {};

  const int srow = t >> 3;                  // 0..31
  const int scol = (t & 7) ^ (srow & 7);    // swizzled global chunk for this lane
  const short* Ag = A + (long)(m0 + srow) * K + scol * 8;
  const short* Bg = Bt + (long)(n0 + srow) * K + scol * 8;
  char* AsB = (char*)As;
  char* BsB = (char*)Bs;
  const int ldsOff = wave * 1024;  // 8 rows x 128 B per wave

  for (int kt = 0; kt < K; kt += 64) {
#pragma unroll
    for (int i = 0; i < 4; ++i) {
      gld_lds16(Ag + kt + (long)(32 * i) * K, AsB + ldsOff + i * 4096);
      gld_lds16(Bg + kt + (long)(32 * i) * K, BsB + ldsOff + i * 4096);
    }
    __syncthreads();

#pragma unroll
    for (int half = 0; half < 2; ++half) {
      short8 a[4], b[4];
#pragma unroll
      for (int mi = 0; mi < 4; ++mi) {
        const int rr = wm + mi * 16 + l15;
        a[mi] = *(const short8*)&As[rr * 64 + (((half << 2) | quad) ^ (rr & 7)) * 8];
      }
#pragma unroll
      for (int ni = 0; ni < 4; ++ni) {
        const int rr = wn + ni * 16 + l15;
        b[ni] = *(const short8*)&Bs[rr * 64 + (((half << 2) | quad) ^ (rr & 7)) * 8];
      }
#pragma unroll
      for (int mi = 0; mi < 4; ++mi)
#pragma unroll
        for (int ni = 0; ni < 4; ++ni)
          acc[mi][ni] = __builtin_amdgcn_mfma_f32_16x16x32_bf16(a[mi], b[ni], acc[mi][ni], 0, 0, 0);
    }
    __syncthreads();
  }

  short* headDst = (which == 0) ? Qh : Kh;
#pragma unroll
  for (int mi = 0; mi < 4; ++mi) {
#pragma unroll
    for (int ni = 0; ni < 4; ++ni) {
#pragma unroll
      for (int r = 0; r < 4; ++r) {
        const int row = m0 + wm + mi * 16 + quad * 4 + r;
        const int col = nl0 + wn + ni * 16 + l15;
        const short v = f2b(acc[mi][ni][r]);
        if (which == 2) {
          vlin[(long)row * 2048 + col] = v;
        } else {
          const int bb = row >> 11, s = row & 2047, h = col >> 7, hd = col & 127;
          headDst[(((long)(bb * 16 + h) * 2048) + s) * 128 + hd] = v;
        }
      }
    }
  }
}

// ---------------- output GEMM: fp32 out, token-major; BK=64 swizzled ----------------
__global__ __launch_bounds__(256) void gemm_out(const short* __restrict__ A,
                                                const short* __restrict__ Bt,
                                                float* __restrict__ Cout) {
  constexpr int K = 2048, N = 2048;
  __shared__ short As[128 * 64];
  __shared__ short Bs[128 * 64];
  const int m0 = blockIdx.y * 128, n0 = blockIdx.x * 128;
  const int t = threadIdx.x;
  const int wave = t >> 6, lane = t & 63, l15 = lane & 15, quad = lane >> 4;
  const int wm = (wave >> 1) * 64, wn = (wave & 1) * 64;

  floatx4 acc[4][4] = {};

  const int srow = t >> 3;
  const int scol = (t & 7) ^ (srow & 7);
  const short* Ag = A + (long)(m0 + srow) * K + scol * 8;
  const short* Bg = Bt + (long)(n0 + srow) * K + scol * 8;
  char* AsB = (char*)As;
  char* BsB = (char*)Bs;
  const int ldsOff = wave * 1024;

  for (int kt = 0; kt < K; kt += 64) {
#pragma unroll
    for (int i = 0; i < 4; ++i) {
      gld_lds16(Ag + kt + (long)(32 * i) * K, AsB + ldsOff + i * 4096);
      gld_lds16(Bg + kt + (long)(32 * i) * K, BsB + ldsOff + i * 4096);
    }
    __syncthreads();

#pragma unroll
    for (int half = 0; half < 2; ++half) {
      short8 a[4], b[4];
#pragma unroll
      for (int mi = 0; mi < 4; ++mi) {
        const int rr = wm + mi * 16 + l15;
        a[mi] = *(const short8*)&As[rr * 64 + (((half << 2) | quad) ^ (rr & 7)) * 8];
      }
#pragma unroll
      for (int ni = 0; ni < 4; ++ni) {
        const int rr = wn + ni * 16 + l15;
        b[ni] = *(const short8*)&Bs[rr * 64 + (((half << 2) | quad) ^ (rr & 7)) * 8];
      }
#pragma unroll
      for (int mi = 0; mi < 4; ++mi)
#pragma unroll
        for (int ni = 0; ni < 4; ++ni)
          acc[mi][ni] = __builtin_amdgcn_mfma_f32_16x16x32_bf16(a[mi], b[ni], acc[mi][ni], 0, 0, 0);
    }
    __syncthreads();
  }

#pragma unroll
  for (int mi = 0; mi < 4; ++mi)
#pragma unroll
    for (int ni = 0; ni < 4; ++ni)
#pragma unroll
      for (int r = 0; r < 4; ++r) {
        const int row = m0 + wm + mi * 16 + quad * 4 + r;
        const int col = n0 + wn + ni * 16 + l15;
        Cout[(long)row * N + col] = acc[mi][ni][r];
      }
}

// ------------- merged RoPE (blocks 0..4095) + V transpose (blocks 4096..6143) -------------
__global__ __launch_bounds__(256) void rope_vtrans(short* __restrict__ Qh,
                                                   short* __restrict__ Kh,
                                                   const float* __restrict__ pos,
                                                   const short* __restrict__ v_lin,
                                                   short* __restrict__ Vt) {
  __shared__ short tile[64 * 72];
  const int bx = blockIdx.x;
  if (bx < 4096) {
    // ---- RoPE in-place on head-major Q,K: 4096 blocks x 256 = token(4096) x h(16) x kk(16)
    const int tid = bx * 256 + threadIdx.x;
    const int kk = tid & 15;
    const int h = (tid >> 4) & 15;
    const int token = tid >> 8;
    const int bb = token >> 11, s = token & 2047;
    const float4 p4 = ((const float4*)pos)[token];
    const float pv[4] = {p4.x, p4.y, p4.z, p4.w};
    const float theta = exp2f(-(float)kk * 0.8304820237218406f);
    const long base = (((long)(bb * 16 + h)) * 2048 + s) * 128 + kk * 8;
    short8 q8 = *(short8*)(Qh + base);
    short8 k8 = *(short8*)(Kh + base);
    short8 qo, ko;
#pragma unroll
    for (int jj = 0; jj < 4; ++jj) {
      const float fr = pv[jj] * theta;
      float sn, c;
      __sincosf(fr, &sn, &c);
      {
        const float tr = b2f(q8[2 * jj]), ti = b2f(q8[2 * jj + 1]);
        qo[2 * jj] = f2b(tr * c - ti * sn);
        qo[2 * jj + 1] = f2b(tr * sn + ti * c);
      }
      {
        const float tr = b2f(k8[2 * jj]), ti = b2f(k8[2 * jj + 1]);
        ko[2 * jj] = f2b(tr * c - ti * sn);
        ko[2 * jj + 1] = f2b(tr * sn + ti * c);
      }
    }
    *(short8*)(Qh + base) = qo;
    *(short8*)(Kh + base) = ko;
  } else {
    // ---- V transpose: vlin [token][h*128+hd] -> Vt [b][h][hd][s] ----
    const int b2 = bx - 4096;  // 0..2047
    const int s0 = (b2 & 31) * 64;
    const int hd0 = ((b2 >> 5) & 1) * 64;
    const int bh = b2 >> 6;
    const int bb = bh >> 4, h = bh & 15;
    const int t = threadIdx.x;
#pragma unroll
    for (int i = 0; i < 2; ++i) {
      const int ch = t + i * 256;
      const int r = ch >> 3, c = ch & 7;
      *(short8*)&tile[r * 72 + c * 8] =
          *(const short8*)(v_lin + (long)(bb * 2048 + s0 + r) * 2048 + h * 128 + hd0 + c * 8);
    }
    __syncthreads();
#pragma unroll
    for (int i = 0; i < 2; ++i) {
      const int ch = t + i * 256;
      const int r2 = ch >> 3, c2 = ch & 7;
      short8 o;
#pragma unroll
      for (int u = 0; u < 8; ++u) o[u] = tile[(c2 * 8 + u) * 72 + r2];
      *(short8*)(Vt + ((long)(bh * 128 + hd0 + r2)) * 2048 + s0 + c2 * 8) = o;
    }
  }
}

// ---------------- flash attention v4: R3 staged structure + XOR-swizzled LDS ----------
// R4 lesson: direct-global K/V regressed 167->289us (load->mfma chains, MfmaUtil 4.9%) —
// LDS staging + prefetch regs was load-bearing. R3 re-read: 167us == 66 steps/CU x 2.5us
// (capacity-bound at ~50% per-step idle), not a 32-step chain.
// R5: keep R3's barrier/staging schedule; shrink LDS 44032->40960 via the qkv-proven
// chunk^(row&7) XOR swizzle (zero measured conflicts) so 4 blocks/CU fit exactly
// (4x40960 = 160KiB), 16 waves/CU. Mirror id map (R4, proven): co-resident blocks
// c,c+256,c+512,c+768 have qt = q0,31-q0,q0,31-q0 -> every CU sums to 66 steps.
__global__ __launch_bounds__(256, 4) void flash(const short* __restrict__ Qh,
                                                const short* __restrict__ Kh,
                                                const short* __restrict__ Vt,
                                                short* __restrict__ ao) {
  __shared__ short Ks[64 * 128];    // 16384 B: row=k (64), 16 chunks of 8sh; phys chunk = (c&8)|((c&7)^(row&7))
  __shared__ short Vts[128 * 64];   // 16384 B: row=hd (128), 8 chunks; phys chunk = c^(row&7)
  __shared__ short Ps[4 * 16 * 64]; // 8192 B: per-wave [16][64], 8 chunks; phys chunk = c^(row&7)
  const int id = blockIdx.x;  // 0..1023
  const int hi = id >> 8, lo = id & 255;
  const int q0 = lo & 31, bl = lo >> 5;
  const int qt = (hi & 1) ? 31 - q0 : q0;   // mirror on odd hi-pages
  const int bh = bl + (hi << 3);            // 0..31, bijective with (qt,bh)
  const int t = threadIdx.x, wave = t >> 6, lane = t & 63, l15 = lane & 15, quad = lane >> 4;
  const int sqb = qt * 64;
  const int lastkt = qt;

  const short* Qbase = Qh + (long)bh * 2048 * 128;
  short8 aq[4];
#pragma unroll
  for (int ks = 0; ks < 4; ++ks)
    aq[ks] = *(const short8*)(Qbase + (long)(sqb + wave * 16 + l15) * 128 + ks * 32 + quad * 8);

  const short* KgBase = Kh + (long)bh * 2048 * 128;
  const short* VgBase = Vt + (long)bh * 128 * 2048;

  short8 kreg[4], vreg[4];
#pragma unroll
  for (int i = 0; i < 4; ++i) {
    const int ch = t + i * 256;
    kreg[i] = *(const short8*)(KgBase + (long)(ch >> 4) * 128 + (ch & 15) * 8);
    vreg[i] = *(const short8*)(VgBase + (long)(ch >> 3) * 2048 + (ch & 7) * 8);
  }

  float l_part[4] = {};
  floatx4 acc_o[8] = {};
  const float CEXP = 0.12751745f;  // (1/sqrt(128)) * log2(e)

  for (int kt = 0; kt <= lastkt; ++kt) {
    const int k0 = kt * 64;
    if (kt > 0) __syncthreads();

    // ---- stage K/V tile kt into swizzled LDS ----
#pragma unroll
    for (int i = 0; i < 4; ++i) {
      const int ch = t + i * 256;
      const int kr = ch >> 4, kc = ch & 15;
      *(short8*)&Ks[kr * 128 + (((kc & 7) ^ (kr & 7)) | (kc & 8)) * 8] = kreg[i];
      const int vr = ch >> 3, vc = ch & 7;
      *(short8*)&Vts[vr * 64 + (vc ^ (vr & 7)) * 8] = vreg[i];
    }
    __syncthreads();

    if (kt < lastkt) {
      const short* Kg = KgBase + (long)(k0 + 64) * 128;
      const short* Vg = VgBase + (k0 + 64);
#pragma unroll
      for (int i = 0; i < 4; ++i) {
        const int ch = t + i * 256;
        kreg[i] = *(const short8*)(Kg + (long)(ch >> 4) * 128 + (ch & 15) * 8);
        vreg[i] = *(const short8*)(Vg + (long)(ch >> 3) * 2048 + (ch & 7) * 8);
      }
    }

    const bool dg = (kt == lastkt);
    floatx4 accs[4] = {};
    __builtin_amdgcn_s_setprio(1);
#pragma unroll
    for (int ks = 0; ks < 4; ++ks) {
#pragma unroll
      for (int ni = 0; ni < 4; ++ni) {
        const int rr = ni * 16 + l15;
        const int c = ks * 4 + quad;  // logical chunk 0..15
        const short8 bk = *(const short8*)&Ks[rr * 128 + (((c & 7) ^ (rr & 7)) | (c & 8)) * 8];
        accs[ni] = __builtin_amdgcn_mfma_f32_16x16x32_bf16(aq[ks], bk, accs[ni], 0, 0, 0);
      }
    }
    __builtin_amdgcn_s_setprio(0);
#pragma unroll
    for (int r = 0; r < 4; ++r) {
      const int qrow = sqb + wave * 16 + quad * 4 + r;
      const int prow = quad * 4 + r;
#pragma unroll
      for (int ni = 0; ni < 4; ++ni) {
        float e = exp2f(accs[ni][r] * CEXP);
        if (dg && (k0 + ni * 16 + l15) > qrow) e = 0.f;
        const int pc = ni * 2 + (l15 >> 3);  // logical chunk 0..7
        Ps[wave * 1024 + prow * 64 + (pc ^ (prow & 7)) * 8 + (l15 & 7)] = f2b(e);
        l_part[r] += e;
      }
    }
    __builtin_amdgcn_s_setprio(1);
#pragma unroll
    for (int ks2 = 0; ks2 < 2; ++ks2) {
      const int pc = ks2 * 4 + quad;  // logical chunk 0..7
      const short8 ap = *(const short8*)&Ps[wave * 1024 + l15 * 64 + (pc ^ (l15 & 7)) * 8];
#pragma unroll
      for (int nh = 0; nh < 8; ++nh) {
        const int vr = nh * 16 + l15;
        const short8 bv = *(const short8*)&Vts[vr * 64 + (pc ^ (vr & 7)) * 8];
        acc_o[nh] = __builtin_amdgcn_mfma_f32_16x16x32_bf16(ap, bv, acc_o[nh], 0, 0, 0);
      }
    }
    __builtin_amdgcn_s_setprio(0);
  }

  const int bb = bh >> 4, h = bh & 15;
#pragma unroll
  for (int r = 0; r < 4; ++r) {
    float rs = l_part[r];
#pragma unroll
    for (int mm = 8; mm >= 1; mm >>= 1) rs += __shfl_xor(rs, mm, 16);
    const float inv = 1.0f / rs;
    const int s = sqb + wave * 16 + quad * 4 + r;
    const long rowbase = ((long)(bb * 2048 + s)) * 2048 + h * 128;
#pragma unroll
    for (int nh = 0; nh < 8; ++nh) ao[rowbase + nh * 16 + l15] = f2b(acc_o[nh][r] * inv);
  }
}

extern "C" void kernel_launch(void* const* d_in, const int* in_sizes, int n_in,
                              void* d_out, int out_size, void* d_ws, size_t ws_size,
                              hipStream_t stream) {
  const float* x = (const float*)d_in[0];
  const float* pos = (const float*)d_in[1];
  const float* wq = (const float*)d_in[3];
  const float* wk = (const float*)d_in[4];
  const float* wv = (const float*)d_in[5];
  const float* wo = (const float*)d_in[6];
  float* out = (float*)d_out;

  char* ws = (char*)d_ws;
  const size_t MB = 1024 * 1024;
  short* xb    = (short*)(ws + 0);        // 16 MB
  short* wqkvb = (short*)(ws + 16 * MB);  // 24 MB
  short* wob   = (short*)(ws + 40 * MB);  // 8 MB
  short* Qh    = (short*)(ws + 48 * MB);  // 16 MB
  short* Kh    = (short*)(ws + 64 * MB);  // 16 MB
  short* Vt    = (short*)(ws + 80 * MB);  // 16 MB
  short* vlin  = (short*)(ws + 96 * MB);  // 16 MB
  short* ao    = (short*)(ws + 96 * MB);  // alias vlin (vtrans consumes vlin before flash)
  // total 112 MB

  cast_all<<<24576, 256, 0, stream>>>(x, wq, wk, wv, wo, xb);

  qkv_gemm<<<dim3(48, 32), 256, 0, stream>>>(xb, wqkvb, Qh, Kh, vlin);

  rope_vtrans<<<6144, 256, 0, stream>>>(Qh, Kh, pos, vlin, Vt);

  flash<<<1024, 256, 0, stream>>>(Qh, Kh, Vt, ao);

  gemm_out<<<dim3(16, 32), 256, 0, stream>>>(ao, wob, out);
}

// Round 6
// 422.646 us; speedup vs baseline: 1.4165x; 1.3789x over previous
//
#include <hip/hip_runtime.h>
#include <cstdint>
#include <type_traits>

typedef __attribute__((ext_vector_type(8))) short short8;
typedef __attribute__((ext_vector_type(4))) float floatx4;

#define NB 2
#define NS 2048
#define ND 2048
#define NH 16
#define NHD 128

__device__ __forceinline__ float b2f(short s) {
  unsigned u = ((unsigned)(unsigned short)s) << 16;
  return __builtin_bit_cast(float, u);
}
__device__ __forceinline__ short f2b(float f) {
  unsigned u = __builtin_bit_cast(unsigned, f);
  unsigned r = (u + 0x7fffu + ((u >> 16) & 1u)) >> 16;
  return (short)(unsigned short)r;
}

// ---------------- fused cast: x|wq|wk|wv|wo -> contiguous bf16 ws [xb|wqkvb|wob] -------
__global__ void cast_all(const float* __restrict__ x, const float* __restrict__ wq,
                         const float* __restrict__ wk, const float* __restrict__ wv,
                         const float* __restrict__ wo, short* __restrict__ dst) {
  const int i = blockIdx.x * blockDim.x + threadIdx.x;  // short4 units, block-uniform ranges
  const float* src;
  int off;
  if (i < 2097152) { src = x;  off = i; }
  else if (i < 3145728) { src = wq; off = i - 2097152; }
  else if (i < 4194304) { src = wk; off = i - 3145728; }
  else if (i < 5242880) { src = wv; off = i - 4194304; }
  else { src = wo; off = i - 5242880; }
  float4 v = ((const float4*)src)[off];
  short4 o;
  o.x = f2b(v.x); o.y = f2b(v.y); o.z = f2b(v.z); o.w = f2b(v.w);
  ((short4*)dst)[i] = o;
}

// ---------------- async global->LDS, 16B/lane ----------------
__device__ __forceinline__ void gld_lds16(const void* g, void* l) {
  __builtin_amdgcn_global_load_lds((const __attribute__((address_space(1))) void*)g,
                                   (__attribute__((address_space(3))) void*)l,
                                   16, 0, 0);
}

// ---------------- fused QKV GEMM, BK=64, XOR-swizzled LDS (proven 128^2, 838 TF) --------
// C = x (4096x2048) * Wqkv^T (6144x2048). col-block: 0-15 Q head-major, 16-31 K head-major,
// 32-47 V token-major. LDS[r][c] holds global chunk c^(r&7) (16B chunks, 8/row).
// R2 lesson: 256^2 4-phase/2-buffer dbuf regressed (vmcnt(0) drain at 1.5-2.5-phase
// distance < HBM latency; XCD swizzle raised FETCH 106->176MB). A retry needs the true
// m201 half-tile ring + counted vmcnt(6).
__global__ __launch_bounds__(256) void qkv_gemm(const short* __restrict__ A,
                                                const short* __restrict__ Bt,
                                                short* __restrict__ Qh,
                                                short* __restrict__ Kh,
                                                short* __restrict__ vlin) {
  constexpr int K = 2048;
  __shared__ short As[128 * 64];
  __shared__ short Bs[128 * 64];
  const int m0 = blockIdx.y * 128, n0 = blockIdx.x * 128;
  const int which = n0 >> 11;
  const int nl0 = n0 & 2047;
  const int t = threadIdx.x;
  const int wave = t >> 6, lane = t & 63, l15 = lane & 15, quad = lane >> 4;
  const int wm = (wave >> 1) * 64, wn = (wave & 1) * 64;

  floatx4 acc[4][4] = {};

  const int srow = t >> 3;                  // 0..31
  const int scol = (t & 7) ^ (srow & 7);    // swizzled global chunk for this lane
  const short* Ag = A + (long)(m0 + srow) * K + scol * 8;
  const short* Bg = Bt + (long)(n0 + srow) * K + scol * 8;
  char* AsB = (char*)As;
  char* BsB = (char*)Bs;
  const int ldsOff = wave * 1024;  // 8 rows x 128 B per wave

  for (int kt = 0; kt < K; kt += 64) {
#pragma unroll
    for (int i = 0; i < 4; ++i) {
      gld_lds16(Ag + kt + (long)(32 * i) * K, AsB + ldsOff + i * 4096);
      gld_lds16(Bg + kt + (long)(32 * i) * K, BsB + ldsOff + i * 4096);
    }
    __syncthreads();

#pragma unroll
    for (int half = 0; half < 2; ++half) {
      short8 a[4], b[4];
#pragma unroll
      for (int mi = 0; mi < 4; ++mi) {
        const int rr = wm + mi * 16 + l15;
        a[mi] = *(const short8*)&As[rr * 64 + (((half << 2) | quad) ^ (rr & 7)) * 8];
      }
#pragma unroll
      for (int ni = 0; ni < 4; ++ni) {
        const int rr = wn + ni * 16 + l15;
        b[ni] = *(const short8*)&Bs[rr * 64 + (((half << 2) | quad) ^ (rr & 7)) * 8];
      }
#pragma unroll
      for (int mi = 0; mi < 4; ++mi)
#pragma unroll
        for (int ni = 0; ni < 4; ++ni)
          acc[mi][ni] = __builtin_amdgcn_mfma_f32_16x16x32_bf16(a[mi], b[ni], acc[mi][ni], 0, 0, 0);
    }
    __syncthreads();
  }

  short* headDst = (which == 0) ? Qh : Kh;
#pragma unroll
  for (int mi = 0; mi < 4; ++mi) {
#pragma unroll
    for (int ni = 0; ni < 4; ++ni) {
#pragma unroll
      for (int r = 0; r < 4; ++r) {
        const int row = m0 + wm + mi * 16 + quad * 4 + r;
        const int col = nl0 + wn + ni * 16 + l15;
        const short v = f2b(acc[mi][ni][r]);
        if (which == 2) {
          vlin[(long)row * 2048 + col] = v;
        } else {
          const int bb = row >> 11, s = row & 2047, h = col >> 7, hd = col & 127;
          headDst[(((long)(bb * 16 + h) * 2048) + s) * 128 + hd] = v;
        }
      }
    }
  }
}

// ---------------- output GEMM: fp32 out, token-major; BK=64 swizzled ----------------
__global__ __launch_bounds__(256) void gemm_out(const short* __restrict__ A,
                                                const short* __restrict__ Bt,
                                                float* __restrict__ Cout) {
  constexpr int K = 2048, N = 2048;
  __shared__ short As[128 * 64];
  __shared__ short Bs[128 * 64];
  const int m0 = blockIdx.y * 128, n0 = blockIdx.x * 128;
  const int t = threadIdx.x;
  const int wave = t >> 6, lane = t & 63, l15 = lane & 15, quad = lane >> 4;
  const int wm = (wave >> 1) * 64, wn = (wave & 1) * 64;

  floatx4 acc[4][4] = {};

  const int srow = t >> 3;
  const int scol = (t & 7) ^ (srow & 7);
  const short* Ag = A + (long)(m0 + srow) * K + scol * 8;
  const short* Bg = Bt + (long)(n0 + srow) * K + scol * 8;
  char* AsB = (char*)As;
  char* BsB = (char*)Bs;
  const int ldsOff = wave * 1024;

  for (int kt = 0; kt < K; kt += 64) {
#pragma unroll
    for (int i = 0; i < 4; ++i) {
      gld_lds16(Ag + kt + (long)(32 * i) * K, AsB + ldsOff + i * 4096);
      gld_lds16(Bg + kt + (long)(32 * i) * K, BsB + ldsOff + i * 4096);
    }
    __syncthreads();

#pragma unroll
    for (int half = 0; half < 2; ++half) {
      short8 a[4], b[4];
#pragma unroll
      for (int mi = 0; mi < 4; ++mi) {
        const int rr = wm + mi * 16 + l15;
        a[mi] = *(const short8*)&As[rr * 64 + (((half << 2) | quad) ^ (rr & 7)) * 8];
      }
#pragma unroll
      for (int ni = 0; ni < 4; ++ni) {
        const int rr = wn + ni * 16 + l15;
        b[ni] = *(const short8*)&Bs[rr * 64 + (((half << 2) | quad) ^ (rr & 7)) * 8];
      }
#pragma unroll
      for (int mi = 0; mi < 4; ++mi)
#pragma unroll
        for (int ni = 0; ni < 4; ++ni)
          acc[mi][ni] = __builtin_amdgcn_mfma_f32_16x16x32_bf16(a[mi], b[ni], acc[mi][ni], 0, 0, 0);
    }
    __syncthreads();
  }

#pragma unroll
  for (int mi = 0; mi < 4; ++mi)
#pragma unroll
    for (int ni = 0; ni < 4; ++ni)
#pragma unroll
      for (int r = 0; r < 4; ++r) {
        const int row = m0 + wm + mi * 16 + quad * 4 + r;
        const int col = n0 + wn + ni * 16 + l15;
        Cout[(long)row * N + col] = acc[mi][ni][r];
      }
}

// ------------- merged RoPE (blocks 0..4095) + V transpose (blocks 4096..6143) -------------
__global__ __launch_bounds__(256) void rope_vtrans(short* __restrict__ Qh,
                                                   short* __restrict__ Kh,
                                                   const float* __restrict__ pos,
                                                   const short* __restrict__ v_lin,
                                                   short* __restrict__ Vt) {
  __shared__ short tile[64 * 72];
  const int bx = blockIdx.x;
  if (bx < 4096) {
    // ---- RoPE in-place on head-major Q,K: 4096 blocks x 256 = token(4096) x h(16) x kk(16)
    const int tid = bx * 256 + threadIdx.x;
    const int kk = tid & 15;
    const int h = (tid >> 4) & 15;
    const int token = tid >> 8;
    const int bb = token >> 11, s = token & 2047;
    const float4 p4 = ((const float4*)pos)[token];
    const float pv[4] = {p4.x, p4.y, p4.z, p4.w};
    const float theta = exp2f(-(float)kk * 0.8304820237218406f);
    const long base = (((long)(bb * 16 + h)) * 2048 + s) * 128 + kk * 8;
    short8 q8 = *(short8*)(Qh + base);
    short8 k8 = *(short8*)(Kh + base);
    short8 qo, ko;
#pragma unroll
    for (int jj = 0; jj < 4; ++jj) {
      const float fr = pv[jj] * theta;
      float sn, c;
      __sincosf(fr, &sn, &c);
      {
        const float tr = b2f(q8[2 * jj]), ti = b2f(q8[2 * jj + 1]);
        qo[2 * jj] = f2b(tr * c - ti * sn);
        qo[2 * jj + 1] = f2b(tr * sn + ti * c);
      }
      {
        const float tr = b2f(k8[2 * jj]), ti = b2f(k8[2 * jj + 1]);
        ko[2 * jj] = f2b(tr * c - ti * sn);
        ko[2 * jj + 1] = f2b(tr * sn + ti * c);
      }
    }
    *(short8*)(Qh + base) = qo;
    *(short8*)(Kh + base) = ko;
  } else {
    // ---- V transpose: vlin [token][h*128+hd] -> Vt [b][h][hd][s] ----
    const int b2 = bx - 4096;  // 0..2047
    const int s0 = (b2 & 31) * 64;
    const int hd0 = ((b2 >> 5) & 1) * 64;
    const int bh = b2 >> 6;
    const int bb = bh >> 4, h = bh & 15;
    const int t = threadIdx.x;
#pragma unroll
    for (int i = 0; i < 2; ++i) {
      const int ch = t + i * 256;
      const int r = ch >> 3, c = ch & 7;
      *(short8*)&tile[r * 72 + c * 8] =
          *(const short8*)(v_lin + (long)(bb * 2048 + s0 + r) * 2048 + h * 128 + hd0 + c * 8);
    }
    __syncthreads();
#pragma unroll
    for (int i = 0; i < 2; ++i) {
      const int ch = t + i * 256;
      const int r2 = ch >> 3, c2 = ch & 7;
      short8 o;
#pragma unroll
      for (int u = 0; u < 8; ++u) o[u] = tile[(c2 * 8 + u) * 72 + r2];
      *(short8*)(Vt + ((long)(bh * 128 + hd0 + r2)) * 2048 + s0 + c2 * 8) = o;
    }
  }
}

// ---------------- flash attention v5: R3 staged structure, spill-free occupancy ----------
// R5 lesson: __launch_bounds__(256,4) forced VGPR 84->64 -> ~650MB scratch spill traffic
// (WRITE_SIZE 22->411MB, FETCH 132->377MB), dur 167->273us. The register file, not LDS,
// is the 4-blocks/CU barrier for this body. Revert to (256,3) (proven spill-free, VGPR 84,
// 12 waves/CU); keep the verified 40,960B XOR-swizzled LDS (passed on HW; conflicts
// 4.87M->4.33M, minor). Next structural lever if more is needed: swapped-QK in-register
// softmax (drops Ps + kreg/vreg pressure) or the faithful m201 8-phase qkv_gemm.
__global__ __launch_bounds__(256, 3) void flash(const short* __restrict__ Qh,
                                                const short* __restrict__ Kh,
                                                const short* __restrict__ Vt,
                                                short* __restrict__ ao) {
  __shared__ short Ks[64 * 128];    // 16384 B: row=k (64), 16 chunks of 8sh; phys chunk = (c&8)|((c&7)^(row&7))
  __shared__ short Vts[128 * 64];   // 16384 B: row=hd (128), 8 chunks; phys chunk = c^(row&7)
  __shared__ short Ps[4 * 16 * 64]; // 8192 B: per-wave [16][64], 8 chunks; phys chunk = c^(row&7)
  const int id = blockIdx.x;  // 0..1023
  const int hi = id >> 8, lo = id & 255;
  const int q0 = lo & 31, bl = lo >> 5;
  const int qt = (hi & 1) ? 31 - q0 : q0;   // mirror on odd hi-pages
  const int bh = bl + (hi << 3);            // 0..31, bijective with (qt,bh)
  const int t = threadIdx.x, wave = t >> 6, lane = t & 63, l15 = lane & 15, quad = lane >> 4;
  const int sqb = qt * 64;
  const int lastkt = qt;

  const short* Qbase = Qh + (long)bh * 2048 * 128;
  short8 aq[4];
#pragma unroll
  for (int ks = 0; ks < 4; ++ks)
    aq[ks] = *(const short8*)(Qbase + (long)(sqb + wave * 16 + l15) * 128 + ks * 32 + quad * 8);

  const short* KgBase = Kh + (long)bh * 2048 * 128;
  const short* VgBase = Vt + (long)bh * 128 * 2048;

  short8 kreg[4], vreg[4];
#pragma unroll
  for (int i = 0; i < 4; ++i) {
    const int ch = t + i * 256;
    kreg[i] = *(const short8*)(KgBase + (long)(ch >> 4) * 128 + (ch & 15) * 8);
    vreg[i] = *(const short8*)(VgBase + (long)(ch >> 3) * 2048 + (ch & 7) * 8);
  }

  float l_part[4] = {};
  floatx4 acc_o[8] = {};
  const float CEXP = 0.12751745f;  // (1/sqrt(128)) * log2(e)

  for (int kt = 0; kt <= lastkt; ++kt) {
    const int k0 = kt * 64;
    if (kt > 0) __syncthreads();

    // ---- stage K/V tile kt into swizzled LDS ----
#pragma unroll
    for (int i = 0; i < 4; ++i) {
      const int ch = t + i * 256;
      const int kr = ch >> 4, kc = ch & 15;
      *(short8*)&Ks[kr * 128 + (((kc & 7) ^ (kr & 7)) | (kc & 8)) * 8] = kreg[i];
      const int vr = ch >> 3, vc = ch & 7;
      *(short8*)&Vts[vr * 64 + (vc ^ (vr & 7)) * 8] = vreg[i];
    }
    __syncthreads();

    if (kt < lastkt) {
      const short* Kg = KgBase + (long)(k0 + 64) * 128;
      const short* Vg = VgBase + (k0 + 64);
#pragma unroll
      for (int i = 0; i < 4; ++i) {
        const int ch = t + i * 256;
        kreg[i] = *(const short8*)(Kg + (long)(ch >> 4) * 128 + (ch & 15) * 8);
        vreg[i] = *(const short8*)(Vg + (long)(ch >> 3) * 2048 + (ch & 7) * 8);
      }
    }

    const bool dg = (kt == lastkt);
    floatx4 accs[4] = {};
    __builtin_amdgcn_s_setprio(1);
#pragma unroll
    for (int ks = 0; ks < 4; ++ks) {
#pragma unroll
      for (int ni = 0; ni < 4; ++ni) {
        const int rr = ni * 16 + l15;
        const int c = ks * 4 + quad;  // logical chunk 0..15
        const short8 bk = *(const short8*)&Ks[rr * 128 + (((c & 7) ^ (rr & 7)) | (c & 8)) * 8];
        accs[ni] = __builtin_amdgcn_mfma_f32_16x16x32_bf16(aq[ks], bk, accs[ni], 0, 0, 0);
      }
    }
    __builtin_amdgcn_s_setprio(0);
#pragma unroll
    for (int r = 0; r < 4; ++r) {
      const int qrow = sqb + wave * 16 + quad * 4 + r;
      const int prow = quad * 4 + r;
#pragma unroll
      for (int ni = 0; ni < 4; ++ni) {
        float e = exp2f(accs[ni][r] * CEXP);
        if (dg && (k0 + ni * 16 + l15) > qrow) e = 0.f;
        const int pc = ni * 2 + (l15 >> 3);  // logical chunk 0..7
        Ps[wave * 1024 + prow * 64 + (pc ^ (prow & 7)) * 8 + (l15 & 7)] = f2b(e);
        l_part[r] += e;
      }
    }
    __builtin_amdgcn_s_setprio(1);
#pragma unroll
    for (int ks2 = 0; ks2 < 2; ++ks2) {
      const int pc = ks2 * 4 + quad;  // logical chunk 0..7
      const short8 ap = *(const short8*)&Ps[wave * 1024 + l15 * 64 + (pc ^ (l15 & 7)) * 8];
#pragma unroll
      for (int nh = 0; nh < 8; ++nh) {
        const int vr = nh * 16 + l15;
        const short8 bv = *(const short8*)&Vts[vr * 64 + (pc ^ (vr & 7)) * 8];
        acc_o[nh] = __builtin_amdgcn_mfma_f32_16x16x32_bf16(ap, bv, acc_o[nh], 0, 0, 0);
      }
    }
    __builtin_amdgcn_s_setprio(0);
  }

  const int bb = bh >> 4, h = bh & 15;
#pragma unroll
  for (int r = 0; r < 4; ++r) {
    float rs = l_part[r];
#pragma unroll
    for (int mm = 8; mm >= 1; mm >>= 1) rs += __shfl_xor(rs, mm, 16);
    const float inv = 1.0f / rs;
    const int s = sqb + wave * 16 + quad * 4 + r;
    const long rowbase = ((long)(bb * 2048 + s)) * 2048 + h * 128;
#pragma unroll
    for (int nh = 0; nh < 8; ++nh) ao[rowbase + nh * 16 + l15] = f2b(acc_o[nh][r] * inv);
  }
}

extern "C" void kernel_launch(void* const* d_in, const int* in_sizes, int n_in,
                              void* d_out, int out_size, void* d_ws, size_t ws_size,
                              hipStream_t stream) {
  const float* x = (const float*)d_in[0];
  const float* pos = (const float*)d_in[1];
  const float* wq = (const float*)d_in[3];
  const float* wk = (const float*)d_in[4];
  const float* wv = (const float*)d_in[5];
  const float* wo = (const float*)d_in[6];
  float* out = (float*)d_out;

  char* ws = (char*)d_ws;
  const size_t MB = 1024 * 1024;
  short* xb    = (short*)(ws + 0);        // 16 MB
  short* wqkvb = (short*)(ws + 16 * MB);  // 24 MB
  short* wob   = (short*)(ws + 40 * MB);  // 8 MB
  short* Qh    = (short*)(ws + 48 * MB);  // 16 MB
  short* Kh    = (short*)(ws + 64 * MB);  // 16 MB
  short* Vt    = (short*)(ws + 80 * MB);  // 16 MB
  short* vlin  = (short*)(ws + 96 * MB);  // 16 MB
  short* ao    = (short*)(ws + 96 * MB);  // alias vlin (vtrans consumes vlin before flash)
  // total 112 MB

  cast_all<<<24576, 256, 0, stream>>>(x, wq, wk, wv, wo, xb);

  qkv_gemm<<<dim3(48, 32), 256, 0, stream>>>(xb, wqkvb, Qh, Kh, vlin);

  rope_vtrans<<<6144, 256, 0, stream>>>(Qh, Kh, pos, vlin, Vt);

  flash<<<1024, 256, 0, stream>>>(Qh, Kh, Vt, ao);

  gemm_out<<<dim3(16, 32), 256, 0, stream>>>(ao, wob, out);
}